// Round 5
// baseline (261.597 us; speedup 1.0000x reference)
//
#include <hip/hip_runtime.h>
#include <math.h>

#define B_   4
#define N_   512
#define T_   128
#define F_   64
#define QT   128
#define NSTR (T_*F_)   // 8192 floats between consecutive n
#define RS   144       // LDS row stride (bytes) for both tiles

typedef __attribute__((ext_vector_type(8))) short  s8v;
typedef __attribute__((ext_vector_type(4))) float  f4v;

union F8 { s8v v; unsigned u[4]; uint2 u2[2]; };

// row-stride-144 tile, 16B-chunk XOR swizzle (col in bf16 ELEMENT units)
__device__ __forceinline__ int swz(int row, int col) {
    return row*RS + ((((col>>3) ^ (row>>3)) & 7) << 4) + ((col & 7) << 1);
}

__device__ __forceinline__ unsigned cvt_pk(float lo, float hi) {
    unsigned r;
    asm("v_cvt_pk_bf16_f32 %0, %1, %2" : "=v"(r) : "v"(lo), "v"(hi));
    return r;
}

#define EXPK 0.18033688f   // 0.125 * log2(e) : exp(s/8) = exp2(s*EXPK)

__global__ __launch_bounds__(256, 4)
void sgcn_mfma4_kernel(const float* __restrict__ x,
                       const float* __restrict__ adj,
                       const float* __restrict__ theta,
                       float* __restrict__ out)
{
    __shared__ char ldsbuf[4*64*RS];   // 36864 B: 2 buffers x {Xrow, Xcol}

    const int tid  = threadIdx.x;
    const int lane = tid & 63;
    const int w    = tid >> 6;       // wave 0..3
    const int c15  = lane & 15;
    const int g4   = lane >> 4;      // 0..3

    const int g  = blockIdx.y;       // group = b*T + t
    const int b  = g >> 7;
    const int t  = g & 127;
    const int q0 = blockIdx.x*QT + 32*w;   // this wave's q-base

    const float* xg = x + (size_t)b*N_*NSTR + (size_t)t*F_;

    // ---- Q as B-fragments (swapped QK: S^T = K * Q^T) ----
    F8 qf[2][2];   // [qt][kk]
    #pragma unroll
    for (int qt = 0; qt < 2; ++qt)
      #pragma unroll
      for (int kk = 0; kk < 2; ++kk) {
        const float* qp = xg + (size_t)(q0 + 16*qt + c15)*NSTR + 32*kk + 8*g4;
        float4 a = *(const float4*)qp;
        float4 c = *(const float4*)(qp + 4);
        qf[qt][kk].u[0] = cvt_pk(a.x, a.y);
        qf[qt][kk].u[1] = cvt_pk(a.z, a.w);
        qf[qt][kk].u[2] = cvt_pk(c.x, c.y);
        qf[qt][kk].u[3] = cvt_pk(c.z, c.w);
      }

    f4v  Oacc[4][2];   // O^T accumulators [ft][qt]
    float l_acc[2] = {0.f, 0.f};
    #pragma unroll
    for (int ft = 0; ft < 4; ++ft)
      #pragma unroll
      for (int qt = 0; qt < 2; ++qt) Oacc[ft][qt] = (f4v)0.f;

    const int nrow = tid >> 4;       // 0..15 staging row (+16*it)
    const int nb   = 4*w;            // quad's n-base within a 16-row slab

    // ---- staging: Xrow direct + Xcol via register 4x4 transpose ----
    auto stage = [&](char* Xr, char* Xc, const float4* xvv) {
        #pragma unroll
        for (int it = 0; it < 4; ++it) {
            int n = nrow + 16*it;
            unsigned p0 = cvt_pk(xvv[it].x, xvv[it].y);
            unsigned p1 = cvt_pk(xvv[it].z, xvv[it].w);
            *(uint2*)(Xr + swz(n, 4*c15)) = make_uint2(p0, p1);

            unsigned t0 = (unsigned)__shfl_xor((int)p0, 16);
            unsigned t1 = (unsigned)__shfl_xor((int)p1, 16);
            unsigned a  = (g4 & 2) ? p1 : p0;
            unsigned ta = (g4 & 2) ? t1 : t0;
            unsigned bq = (g4 & 2) ? p0 : p1;
            unsigned tb = (g4 & 2) ? t0 : t1;
            unsigned u_mine = (g4 & 1) ? ((ta >> 16) | (a  & 0xffff0000u))
                                       : ((a  & 0xffffu) | (ta << 16));
            unsigned u_oth  = (g4 & 1) ? ((tb >> 16) | (bq & 0xffff0000u))
                                       : ((bq & 0xffffu) | (tb << 16));
            unsigned v2 = (unsigned)__shfl_xor((int)u_oth, 32);
            uint2 wv = (g4 & 2) ? make_uint2(v2, u_mine) : make_uint2(u_mine, v2);
            *(uint2*)(Xc + swz(4*c15 + g4, nb + 16*it)) = wv;
        }
    };

    // ---- prologue: load + stage k-tile 0 into buffer 0 ----
    float4 xv[4];
    #pragma unroll
    for (int it = 0; it < 4; ++it)
        xv[it] = *(const float4*)(xg + (size_t)(nrow + 16*it)*NSTR + 4*c15);
    stage(ldsbuf, ldsbuf + 64*RS, xv);

    for (int kt = 0; kt < 8; ++kt) {
        __syncthreads();   // buf[kt&1] staged; buf[kt&1 ^1] reads (tile kt-1) done

        char* XrowC = ldsbuf + (size_t)(kt & 1) * (2*64*RS);
        char* XcolC = XrowC + 64*RS;
        char* XrowN = ldsbuf + (size_t)((kt & 1) ^ 1) * (2*64*RS);
        char* XcolN = XrowN + 64*RS;

        // issue next-tile global loads early (T14: issue-early / write-late)
        if (kt < 7) {
            #pragma unroll
            for (int it = 0; it < 4; ++it)
                xv[it] = *(const float4*)(xg + (size_t)((kt+1)*64 + nrow + 16*it)*NSTR + 4*c15);
        }

        // adj tile: adj[q][kt*64 + 16mt + 4g4 .. +3]
        float4 adjv[2][4];
        #pragma unroll
        for (int qt = 0; qt < 2; ++qt)
          #pragma unroll
          for (int mt = 0; mt < 4; ++mt)
            adjv[qt][mt] = *(const float4*)(adj + (size_t)(q0 + 16*qt + c15)*N_ + kt*64 + 16*mt + 4*g4);

        // ---- QK^T swapped: S^T[m][q] ----
        f4v S[4][2];
        #pragma unroll
        for (int mt = 0; mt < 4; ++mt)
          #pragma unroll
          for (int qt = 0; qt < 2; ++qt) S[mt][qt] = (f4v)0.f;

        #pragma unroll
        for (int kk = 0; kk < 2; ++kk)
          #pragma unroll
          for (int mt = 0; mt < 4; ++mt) {
            F8 af;   // A: row = c15 (m), k = 8g4+j (f)
            af.v = *(const s8v*)(XrowC + swz(16*mt + c15, 32*kk + 8*g4));
            #pragma unroll
            for (int qt = 0; qt < 2; ++qt)
              S[mt][qt] = __builtin_amdgcn_mfma_f32_16x16x32_bf16(af.v, qf[qt][kk].v, S[mt][qt], 0, 0, 0);
          }

        // ---- softmax numerators (bounded logits; P^T lane-local -> PV B-frags) ----
        F8 pb[2][2];   // [qt][kk]
        #pragma unroll
        for (int qt = 0; qt < 2; ++qt)
          #pragma unroll
          for (int mt = 0; mt < 4; ++mt) {
            float e0 = __builtin_amdgcn_exp2f(S[mt][qt][0] * EXPK);
            float e1 = __builtin_amdgcn_exp2f(S[mt][qt][1] * EXPK);
            float e2 = __builtin_amdgcn_exp2f(S[mt][qt][2] * EXPK);
            float e3 = __builtin_amdgcn_exp2f(S[mt][qt][3] * EXPK);
            l_acc[qt] += (e0 + e1) + (e2 + e3);
            float4 av = adjv[qt][mt];
            pb[qt][mt>>1].u[2*(mt&1)  ] = cvt_pk(e0*av.x, e1*av.y);
            pb[qt][mt>>1].u[2*(mt&1)+1] = cvt_pk(e2*av.z, e3*av.w);
          }

        // ---- stage next tile into the other buffer (write-late) ----
        if (kt < 7) stage(XrowN, XcolN, xv);

        // ---- PV swapped: O^T[f][q] += V^T[f][m] P^T[m][q] ----
        // A k-map (ELEMENT-unit cols, matches pb): j0..3 -> m = 32kk+4g4+j,
        //                                          j4..7 -> m = 32kk+16+4g4+(j-4)
        #pragma unroll
        for (int kk = 0; kk < 2; ++kk)
          #pragma unroll
          for (int ft = 0; ft < 4; ++ft) {
            F8 vf;
            vf.u2[0] = *(const uint2*)(XcolC + swz(16*ft + c15, 32*kk + 4*g4));
            vf.u2[1] = *(const uint2*)(XcolC + swz(16*ft + c15, 32*kk + 16 + 4*g4));
            #pragma unroll
            for (int qt = 0; qt < 2; ++qt)
              Oacc[ft][qt] = __builtin_amdgcn_mfma_f32_16x16x32_bf16(vf.v, pb[qt][kk].v, Oacc[ft][qt], 0, 0, 0);
          }
    }

    // ---- softmax denominators ----
    float inv[2];
    #pragma unroll
    for (int qt = 0; qt < 2; ++qt) {
        float lv = l_acc[qt];
        lv += __shfl_xor(lv, 16);
        lv += __shfl_xor(lv, 32);
        inv[qt] = 0.125f / lv;
    }

    // ---- B-frags from O^T (lane-local), scaled ----
    F8 ob[2][2];
    #pragma unroll
    for (int qt = 0; qt < 2; ++qt)
      #pragma unroll
      for (int kk = 0; kk < 2; ++kk) {
        f4v o0 = Oacc[2*kk][qt], o1 = Oacc[2*kk+1][qt];
        ob[qt][kk].u[0] = cvt_pk(o0[0]*inv[qt], o0[1]*inv[qt]);
        ob[qt][kk].u[1] = cvt_pk(o0[2]*inv[qt], o0[3]*inv[qt]);
        ob[qt][kk].u[2] = cvt_pk(o1[0]*inv[qt], o1[1]*inv[qt]);
        ob[qt][kk].u[3] = cvt_pk(o1[2]*inv[qt], o1[3]*inv[qt]);
      }

    // ---- Theta A-frags (same k-permutation as ob) ----
    F8 tf[4][2];
    #pragma unroll
    for (int ot = 0; ot < 4; ++ot)
      #pragma unroll
      for (int kk = 0; kk < 2; ++kk) {
        const float* tp = theta + (size_t)(16*ot + c15)*F_ + 32*kk + 4*g4;
        float4 a = *(const float4*)tp;          // fi = 32kk+4g4 + 0..3
        float4 c = *(const float4*)(tp + 16);   // fi = 32kk+16+4g4 + 0..3
        tf[ot][kk].u[0] = cvt_pk(a.x, a.y);
        tf[ot][kk].u[1] = cvt_pk(a.z, a.w);
        tf[ot][kk].u[2] = cvt_pk(c.x, c.y);
        tf[ot][kk].u[3] = cvt_pk(c.z, c.w);
      }

    // ---- R^T = Theta * (O^T * inv), relu, store ----
    f4v R[4][2];
    #pragma unroll
    for (int ot = 0; ot < 4; ++ot)
      #pragma unroll
      for (int qt = 0; qt < 2; ++qt) R[ot][qt] = (f4v)0.f;

    #pragma unroll
    for (int kk = 0; kk < 2; ++kk)
      #pragma unroll
      for (int ot = 0; ot < 4; ++ot)
        #pragma unroll
        for (int qt = 0; qt < 2; ++qt)
          R[ot][qt] = __builtin_amdgcn_mfma_f32_16x16x32_bf16(tf[ot][kk].v, ob[qt][kk].v, R[ot][qt], 0, 0, 0);

    #pragma unroll
    for (int ot = 0; ot < 4; ++ot)
      #pragma unroll
      for (int qt = 0; qt < 2; ++qt) {
        float4 v;
        v.x = fmaxf(R[ot][qt][0], 0.f);
        v.y = fmaxf(R[ot][qt][1], 0.f);
        v.z = fmaxf(R[ot][qt][2], 0.f);
        v.w = fmaxf(R[ot][qt][3], 0.f);
        int q  = q0 + 16*qt + c15;
        int fo = 16*ot + 4*g4;
        *(float4*)(out + ((size_t)(b*N_ + q)*T_ + t)*F_ + fo) = v;
      }
}

extern "C" void kernel_launch(void* const* d_in, const int* in_sizes, int n_in,
                              void* d_out, int out_size, void* d_ws, size_t ws_size,
                              hipStream_t stream) {
    const float* x     = (const float*)d_in[0];
    const float* adj   = (const float*)d_in[1];
    const float* theta = (const float*)d_in[2];
    float* out = (float*)d_out;

    dim3 grid(N_ / QT, B_ * T_);   // (4, 512) = 2048 blocks
    sgcn_mfma4_kernel<<<grid, 256, 0, stream>>>(x, adj, theta, out);
}

// Round 6
// 107.284 us; speedup vs baseline: 2.4384x; 2.4384x over previous
//
#include <hip/hip_runtime.h>
#include <math.h>

#define B_   4
#define N_   512
#define T_   128
#define F_   64
#define QT   128
#define NSTR (T_*F_)   // 8192 floats between consecutive n
#define RS   144       // LDS row stride (bytes) for both tiles

typedef __attribute__((ext_vector_type(8))) short  s8v;
typedef __attribute__((ext_vector_type(4))) float  f4v;

union F8 { s8v v; unsigned u[4]; uint2 u2[2]; };

// row-stride-144 tile, 16B-chunk XOR swizzle (col in bf16 ELEMENT units)
__device__ __forceinline__ int swz(int row, int col) {
    return row*RS + ((((col>>3) ^ (row>>3)) & 7) << 4) + ((col & 7) << 1);
}

__device__ __forceinline__ unsigned cvt_pk(float lo, float hi) {
    unsigned r;
    asm("v_cvt_pk_bf16_f32 %0, %1, %2" : "=v"(r) : "v"(lo), "v"(hi));
    return r;
}

#define EXPK 0.18033688f   // 0.125 * log2(e) : exp(s/8) = exp2(s*EXPK)

__global__ __launch_bounds__(256, 3)
void sgcn_mfma5_kernel(const float* __restrict__ x,
                       const float* __restrict__ adj,
                       const float* __restrict__ theta,
                       float* __restrict__ out)
{
    __shared__ char ldsbuf[4*64*RS];   // 36864 B: 2 buffers x {Xrow, Xcol}

    const int tid  = threadIdx.x;
    const int lane = tid & 63;
    const int w    = tid >> 6;       // wave 0..3
    const int c15  = lane & 15;
    const int g4   = lane >> 4;      // 0..3

    const int g  = blockIdx.y;       // group = b*T + t
    const int b  = g >> 7;
    const int t  = g & 127;
    const int q0 = blockIdx.x*QT + 32*w;   // this wave's q-base

    const float* xg = x + (size_t)b*N_*NSTR + (size_t)t*F_;

    // ---- Q as B-fragments (swapped QK: S^T = K * Q^T) ----
    F8 qf[2][2];   // [qt][kk]
    #pragma unroll
    for (int qt = 0; qt < 2; ++qt)
      #pragma unroll
      for (int kk = 0; kk < 2; ++kk) {
        const float* qp = xg + (size_t)(q0 + 16*qt + c15)*NSTR + 32*kk + 8*g4;
        float4 a = *(const float4*)qp;
        float4 c = *(const float4*)(qp + 4);
        qf[qt][kk].u[0] = cvt_pk(a.x, a.y);
        qf[qt][kk].u[1] = cvt_pk(a.z, a.w);
        qf[qt][kk].u[2] = cvt_pk(c.x, c.y);
        qf[qt][kk].u[3] = cvt_pk(c.z, c.w);
      }

    f4v  Oacc[4][2];   // O^T accumulators [ft][qt]
    float l_acc[2] = {0.f, 0.f};
    #pragma unroll
    for (int ft = 0; ft < 4; ++ft)
      #pragma unroll
      for (int qt = 0; qt < 2; ++qt) Oacc[ft][qt] = (f4v)0.f;

    const int nrow = tid >> 4;       // = 4w + g4 : staging row (+16*it)

    // ---- staging: Xrow direct + Xcol via register 4x4 transpose ----
    // Xcol storage column for m = 4w+16it+r is 32*(it>>1) + 8w + 4*(it&1) + r,
    // so PV A-frag slot j (k=8g4+j) at col 32kk+8g4+j holds
    // m = 16*(2kk + (j>=4)) + 4g4 + (j&3)  — matches pb's k-map.
    auto stage = [&](char* Xr, char* Xc, const float4* xvv) {
        #pragma unroll
        for (int it = 0; it < 4; ++it) {
            int n = nrow + 16*it;
            unsigned p0 = cvt_pk(xvv[it].x, xvv[it].y);
            unsigned p1 = cvt_pk(xvv[it].z, xvv[it].w);
            *(uint2*)(Xr + swz(n, 4*c15)) = make_uint2(p0, p1);

            unsigned t0 = (unsigned)__shfl_xor((int)p0, 16);
            unsigned t1 = (unsigned)__shfl_xor((int)p1, 16);
            unsigned a  = (g4 & 2) ? p1 : p0;
            unsigned ta = (g4 & 2) ? t1 : t0;
            unsigned bq = (g4 & 2) ? p0 : p1;
            unsigned tb = (g4 & 2) ? t0 : t1;
            unsigned u_mine = (g4 & 1) ? ((ta >> 16) | (a  & 0xffff0000u))
                                       : ((a  & 0xffffu) | (ta << 16));
            unsigned u_oth  = (g4 & 1) ? ((tb >> 16) | (bq & 0xffff0000u))
                                       : ((bq & 0xffffu) | (tb << 16));
            unsigned v2 = (unsigned)__shfl_xor((int)u_oth, 32);
            uint2 wv = (g4 & 2) ? make_uint2(v2, u_mine) : make_uint2(u_mine, v2);
            *(uint2*)(Xc + swz(4*c15 + g4, 32*(it>>1) + 8*w + 4*(it&1))) = wv;
        }
    };

    // ---- prologue: load + stage k-tile 0 into buffer 0 ----
    float4 xv[4];
    #pragma unroll
    for (int it = 0; it < 4; ++it)
        xv[it] = *(const float4*)(xg + (size_t)(nrow + 16*it)*NSTR + 4*c15);
    stage(ldsbuf, ldsbuf + 64*RS, xv);

    for (int kt = 0; kt < 8; ++kt) {
        __syncthreads();   // buf[kt&1] staged; reads of buf[kt&1 ^1] done

        char* XrowC = ldsbuf + (size_t)(kt & 1) * (2*64*RS);
        char* XcolC = XrowC + 64*RS;
        char* XrowN = ldsbuf + (size_t)((kt & 1) ^ 1) * (2*64*RS);
        char* XcolN = XrowN + 64*RS;

        // issue next-tile global loads early (T14: issue-early / write-late)
        if (kt < 7) {
            #pragma unroll
            for (int it = 0; it < 4; ++it)
                xv[it] = *(const float4*)(xg + (size_t)((kt+1)*64 + nrow + 16*it)*NSTR + 4*c15);
        }

        // ---- QK^T + softmax, per mt (keeps S/adj live ranges tiny) ----
        F8 pb[2][2];   // [qt][kk] PV B-frags
        #pragma unroll
        for (int mt = 0; mt < 4; ++mt) {
            float4 av[2];
            #pragma unroll
            for (int qt = 0; qt < 2; ++qt)
                av[qt] = *(const float4*)(adj + (size_t)(q0 + 16*qt + c15)*N_ + kt*64 + 16*mt + 4*g4);

            F8 af0, af1;   // A: row = c15 (m), k = 8g4+j (f)
            af0.v = *(const s8v*)(XrowC + swz(16*mt + c15, 8*g4));
            af1.v = *(const s8v*)(XrowC + swz(16*mt + c15, 32 + 8*g4));

            #pragma unroll
            for (int qt = 0; qt < 2; ++qt) {
                f4v s = (f4v)0.f;
                s = __builtin_amdgcn_mfma_f32_16x16x32_bf16(af0.v, qf[qt][0].v, s, 0, 0, 0);
                s = __builtin_amdgcn_mfma_f32_16x16x32_bf16(af1.v, qf[qt][1].v, s, 0, 0, 0);
                float e0 = __builtin_amdgcn_exp2f(s[0] * EXPK);
                float e1 = __builtin_amdgcn_exp2f(s[1] * EXPK);
                float e2 = __builtin_amdgcn_exp2f(s[2] * EXPK);
                float e3 = __builtin_amdgcn_exp2f(s[3] * EXPK);
                l_acc[qt] += (e0 + e1) + (e2 + e3);
                pb[qt][mt>>1].u[2*(mt&1)  ] = cvt_pk(e0*av[qt].x, e1*av[qt].y);
                pb[qt][mt>>1].u[2*(mt&1)+1] = cvt_pk(e2*av[qt].z, e3*av[qt].w);
            }
        }

        // ---- stage next tile into the other buffer (write-late) ----
        if (kt < 7) stage(XrowN, XcolN, xv);

        // ---- PV: O^T[f][q] += V^T[f][m] P^T[m][q], A-frag = one b128 ----
        #pragma unroll
        for (int kk = 0; kk < 2; ++kk)
          #pragma unroll
          for (int ft = 0; ft < 4; ++ft) {
            F8 vf;
            vf.v = *(const s8v*)(XcolC + swz(16*ft + c15, 32*kk + 8*g4));
            #pragma unroll
            for (int qt = 0; qt < 2; ++qt)
              Oacc[ft][qt] = __builtin_amdgcn_mfma_f32_16x16x32_bf16(vf.v, pb[qt][kk].v, Oacc[ft][qt], 0, 0, 0);
          }
    }

    // ---- softmax denominators ----
    float inv[2];
    #pragma unroll
    for (int qt = 0; qt < 2; ++qt) {
        float lv = l_acc[qt];
        lv += __shfl_xor(lv, 16);
        lv += __shfl_xor(lv, 32);
        inv[qt] = 0.125f / lv;
    }

    // ---- B-frags from O^T (lane-local), scaled ----
    F8 ob[2][2];
    #pragma unroll
    for (int qt = 0; qt < 2; ++qt)
      #pragma unroll
      for (int kk = 0; kk < 2; ++kk) {
        f4v o0 = Oacc[2*kk][qt], o1 = Oacc[2*kk+1][qt];
        ob[qt][kk].u[0] = cvt_pk(o0[0]*inv[qt], o0[1]*inv[qt]);
        ob[qt][kk].u[1] = cvt_pk(o0[2]*inv[qt], o0[3]*inv[qt]);
        ob[qt][kk].u[2] = cvt_pk(o1[0]*inv[qt], o1[1]*inv[qt]);
        ob[qt][kk].u[3] = cvt_pk(o1[2]*inv[qt], o1[3]*inv[qt]);
      }

    // ---- Theta A-frags (same k-permutation as ob) ----
    F8 tf[4][2];
    #pragma unroll
    for (int ot = 0; ot < 4; ++ot)
      #pragma unroll
      for (int kk = 0; kk < 2; ++kk) {
        const float* tp = theta + (size_t)(16*ot + c15)*F_ + 32*kk + 4*g4;
        float4 a = *(const float4*)tp;          // fi = 32kk+4g4 + 0..3
        float4 c = *(const float4*)(tp + 16);   // fi = 32kk+16+4g4 + 0..3
        tf[ot][kk].u[0] = cvt_pk(a.x, a.y);
        tf[ot][kk].u[1] = cvt_pk(a.z, a.w);
        tf[ot][kk].u[2] = cvt_pk(c.x, c.y);
        tf[ot][kk].u[3] = cvt_pk(c.z, c.w);
      }

    // ---- R^T = Theta * (O^T * inv), relu, store ----
    f4v R[4][2];
    #pragma unroll
    for (int ot = 0; ot < 4; ++ot)
      #pragma unroll
      for (int qt = 0; qt < 2; ++qt) R[ot][qt] = (f4v)0.f;

    #pragma unroll
    for (int kk = 0; kk < 2; ++kk)
      #pragma unroll
      for (int ot = 0; ot < 4; ++ot)
        #pragma unroll
        for (int qt = 0; qt < 2; ++qt)
          R[ot][qt] = __builtin_amdgcn_mfma_f32_16x16x32_bf16(tf[ot][kk].v, ob[qt][kk].v, R[ot][qt], 0, 0, 0);

    #pragma unroll
    for (int ot = 0; ot < 4; ++ot)
      #pragma unroll
      for (int qt = 0; qt < 2; ++qt) {
        float4 v;
        v.x = fmaxf(R[ot][qt][0], 0.f);
        v.y = fmaxf(R[ot][qt][1], 0.f);
        v.z = fmaxf(R[ot][qt][2], 0.f);
        v.w = fmaxf(R[ot][qt][3], 0.f);
        int q  = q0 + 16*qt + c15;
        int fo = 16*ot + 4*g4;
        *(float4*)(out + ((size_t)(b*N_ + q)*T_ + t)*F_ + fo) = v;
      }
}

extern "C" void kernel_launch(void* const* d_in, const int* in_sizes, int n_in,
                              void* d_out, int out_size, void* d_ws, size_t ws_size,
                              hipStream_t stream) {
    const float* x     = (const float*)d_in[0];
    const float* adj   = (const float*)d_in[1];
    const float* theta = (const float*)d_in[2];
    float* out = (float*)d_out;

    dim3 grid(N_ / QT, B_ * T_);   // (4, 512) = 2048 blocks
    sgcn_mfma5_kernel<<<grid, 256, 0, stream>>>(x, adj, theta, out);
}